// Round 9
// baseline (204.079 us; speedup 1.0000x reference)
//
#include <hip/hip_runtime.h>
#include <cstdint>

#define BN_EPS 1e-5f

static constexpr int NB = 8192;
static constexpr int JLIN = 500;

// ---------------------------------------------------------------------------
// ws layout
//  h2b   [8192][128] u32   @ 0         4 MB   (row-major per sample)
//  wlin4 [8][32][64][4] u32 @ 4718592  256 KB (per-jw LDS image: kq, j, q)
//  cdat  [640]       u32   @ 4980736   (masks plane-major [tap][c] + T[c] @576)
//  lut   [512]       u32   @ 4983296
//  wout  [10*16]     u32   @ 4985344   (read as u64[8] per o)
//  Tlin  [512]       i32   @ 4985984
//  Bs    [8192]      i32   @ 4988032   32 KB
// ---------------------------------------------------------------------------

// ---------------------------------------------------------------------------
// pack kernel, grid = 258 blocks:
//  blocks 0..249  : wlin direct per-thread packing (thread = (j,k) word,
//                   7-8 aligned float4 loads, no cross-lane ops)
//  blocks 250,251 : conv1 LUT (LDS-staged)
//  blocks 252..257: cdat masks | Tc2 | Tlin | wout
// ---------------------------------------------------------------------------
__global__ __launch_bounds__(256) void pack_kernel(
    const float* __restrict__ conv1_w, const float* __restrict__ conv1_b,
    const float* __restrict__ conv2_w, const float* __restrict__ conv2_b,
    const float* __restrict__ lin_w, const float* __restrict__ lin_b,
    const float* __restrict__ out_w,
    const float* __restrict__ bn1_g, const float* __restrict__ bn1_b,
    const float* __restrict__ bn1_m, const float* __restrict__ bn1_v,
    const float* __restrict__ bn2_g, const float* __restrict__ bn2_b,
    const float* __restrict__ bn2_m, const float* __restrict__ bn2_v,
    uint32_t* __restrict__ wlin4, uint32_t* __restrict__ cdat,
    uint32_t* __restrict__ lut, uint32_t* __restrict__ wout,
    int* __restrict__ Tlin)
{
    __shared__ float    s_c1w[288];
    __shared__ uint32_t s_wp[32];
    __shared__ float    s_inv1[32], s_sh1[32], s_b1[32];

    int tid = threadIdx.x;
    int b   = blockIdx.x;

    if (b < 250) {
        // ---- wlin: one packed word per thread ----
        int idx = b * 256 + tid;            // 0..63999
        int j = idx >> 7, k = idx & 127;
        int c = k >> 1, hi = k & 1;
        const float4* s4 = (const float4*)(lin_w + (size_t)j * 3840 + c * 60 + hi * 32);
        int nq = hi ? 7 : 8;                // 28 or 32 bits
        uint32_t word = 0;
        for (int qq = 0; qq < nq; ++qq) {
            float4 v = s4[qq];
            word |= (v.x > 0.0f ? 1u : 0u) << (4 * qq);
            word |= (v.y > 0.0f ? 1u : 0u) << (4 * qq + 1);
            word |= (v.z > 0.0f ? 1u : 0u) << (4 * qq + 2);
            word |= (v.w > 0.0f ? 1u : 0u) << (4 * qq + 3);
        }
        int jw = j >> 6, jl = j & 63, kq = k >> 2, q = k & 3;
        wlin4[jw * 8192 + kq * 256 + jl * 4 + q] = word;
        return;
    }

    int mb = b - 250;
    if (mb < 2) {
        // ---- conv1 LUT, LDS-staged ----
        for (int i = tid; i < 288; i += 256) s_c1w[i] = conv1_w[i];
        __syncthreads();
        if (tid < 32) {
            uint32_t wp = 0;
            for (int t = 0; t < 9; ++t)
                wp |= (s_c1w[tid * 9 + t] < 0.0f ? 1u : 0u) << t;
            s_wp[tid] = wp;
            float inv = bn1_g[tid] / sqrtf(bn1_v[tid] + BN_EPS);
            s_inv1[tid] = inv;
            s_sh1[tid]  = bn1_b[tid] - bn1_m[tid] * inv;
            s_b1[tid]   = conv1_b[tid];
        }
        __syncthreads();
        uint32_t px = (uint32_t)(mb * 256 + tid);     // 0..511
        uint32_t word = 0;
        for (int c = 0; c < 32; ++c) {
            int d = 9 - 2 * __popc(px ^ s_wp[c]);
            float z = __fadd_rn((float)d, s_b1[c]);
            z = __fadd_rn(__fmul_rn(z, s_inv1[c]), s_sh1[c]);
            word |= (z > 0.0f ? 1u : 0u) << c;
        }
        lut[px] = word;
        return;
    }

    int idx = (mb - 2) * 256 + tid;     // 0..1535
    if (idx < 576) {
        // conv2 masks, plane-major [tap][c] (complemented when inv < 0)
        int c = idx / 9, tap = idx % 9;
        uint32_t w = 0;
        for (int ic = 0; ic < 32; ++ic)
            w |= (conv2_w[c * 288 + ic * 9 + tap] > 0.0f ? 1u : 0u) << ic;
        float inv = bn2_g[c] / sqrtf(bn2_v[c] + BN_EPS);
        if (inv < 0.0f) w = ~w;
        cdat[tap * 64 + c] = w;
    } else if (idx < 576 + 64) {
        // conv2 integer thresholds
        int c = idx - 576;
        float inv = bn2_g[c] / sqrtf(bn2_v[c] + BN_EPS);
        float sh  = bn2_b[c] - bn2_m[c] * inv;
        float b2  = conv2_b[c];
        int T = 10000;
        for (int u = -300; u <= 300; ++u) {
            float v = (inv < 0.0f) ? (float)(-u) : (float)u;
            float z = __fadd_rn(__fmul_rn(__fadd_rn(v, b2), inv), sh);
            if (z > 0.0f) { T = u; break; }
        }
        cdat[576 + c] = (uint32_t)T;
    } else if (idx < 576 + 64 + 512) {
        // lin integer thresholds
        int j = idx - (576 + 64);
        int T = 10000;
        if (j < JLIN) {
            float lb = lin_b[j];
            int base = (int)floorf(-lb) - 2;
            for (int u = base; u <= base + 5; ++u)
                if (__fadd_rn((float)u, lb) > 0.0f) { T = u; break; }
        }
        Tlin[j] = T;
    } else if (idx < 576 + 64 + 512 + 160) {
        int t = idx - (576 + 64 + 512);
        int j = t >> 4, k = t & 15;
        uint32_t w = 0;
        for (int bb = 0; bb < 32; ++bb) {
            int jj = k * 32 + bb;
            if (jj < JLIN) w |= (out_w[j * 500 + jj] > 0.0f ? 1u : 0u) << bb;
        }
        wout[t] = w;
    }
}

// ---------------------------------------------------------------------------
// conv kernel: 4 samples/block (wave = sample), 2048 blocks. Unchanged (R8).
// ---------------------------------------------------------------------------
__global__ __launch_bounds__(256) void conv_kernel(
    const float* __restrict__ x,
    const uint32_t* __restrict__ cdat,
    const uint32_t* __restrict__ lut,
    uint32_t* __restrict__ h2b, int* __restrict__ Bs)
{
    __shared__ __align__(8) uint32_t s_flat[4][44];
    __shared__ uint32_t s_lut[512];
    __shared__ __align__(8) uint32_t s_in[4][288];   // 286 used
    __shared__ uint32_t s_base[4][64];

    int tid  = threadIdx.x;
    int lane = tid & 63;
    int wv   = tid >> 6;
    int s    = blockIdx.x * 4 + wv;

    s_lut[tid]       = lut[tid];
    s_lut[tid + 256] = lut[tid + 256];

    // ph1: flat sign bitmap (1296 bits -> 21 ballots, coalesced)
    const float* xs = x + (size_t)s * 1296;
    #pragma unroll
    for (int it = 0; it < 21; ++it) {
        int f = it * 64 + lane;
        float v = (f < 1296) ? xs[f] : 1.0f;
        uint64_t mk = __ballot(v < 0.0f);
        if (lane == 0) *((uint64_t*)&s_flat[wv][2 * it]) = mk;
    }
    __syncthreads();

    // ph2: conv1 via LUT
    for (int i = tid; i < 4 * 286; i += 256) {
        int sl = i / 286, p = i - sl * 286;
        int oy = p / 26, ox = p - oy * 26;
        uint32_t pxb = 0;
        #pragma unroll
        for (int ky = 0; ky < 3; ++ky) {
            int bitpos = 54 * (2 * oy + ky) + 2 * ox;
            int d  = bitpos >> 5;
            int sh = bitpos & 31;
            uint64_t wp = (uint64_t)s_flat[sl][d] | ((uint64_t)s_flat[sl][d + 1] << 32);
            pxb |= (((uint32_t)(wp >> sh)) & 7u) << (3 * ky);
        }
        s_in[sl][p] = s_lut[pxb];
    }
    __syncthreads();

    // ph2.5: window popcount base per output position
    for (int i = tid; i < 4 * 60; i += 256) {
        int sl = i / 60, p = i - sl * 60;
        int oy = p / 12, ox = p - 12 * oy;
        uint32_t sum = 0;
        #pragma unroll
        for (int ky = 0; ky < 3; ++ky) {
            const uint32_t* rp = &s_in[sl][(2 * oy + ky) * 26 + 2 * ox];
            sum += __popc(rp[0]) + __popc(rp[1]) + __popc(rp[2]);
        }
        s_base[sl][p] = sum;
    }
    __syncthreads();

    // ph3: lane = channel; row-at-a-time to bound register pressure
    int c = lane;
    uint32_t m[9];
    #pragma unroll
    for (int q = 0; q < 9; ++q) m[q] = cdat[q * 64 + c];   // coalesced
    int T = (int)cdat[576 + c];

    uint64_t acc = 0;
    for (int oy = 0; oy < 5; ++oy) {
        int P[12];
        #pragma unroll
        for (int ox = 0; ox < 12; ++ox) P[ox] = 0;
        #pragma unroll
        for (int ky = 0; ky < 3; ++ky) {
            const uint32_t* rp = &s_in[wv][(2 * oy + ky) * 26];
            uint32_t r[25];
            #pragma unroll
            for (int d = 0; d < 12; ++d)
                *(uint64_t*)&r[2 * d] = *(const uint64_t*)&rp[2 * d];  // b64 broadcast
            r[24] = rp[24];
            uint32_t m0 = m[ky * 3 + 0], m1 = m[ky * 3 + 1], m2 = m[ky * 3 + 2];
            #pragma unroll
            for (int ox = 0; ox < 12; ++ox) {
                P[ox] += __popc(r[2 * ox]     & m0);
                P[ox] += __popc(r[2 * ox + 1] & m1);
                P[ox] += __popc(r[2 * ox + 2] & m2);
            }
        }
        const uint32_t* bp = &s_base[wv][oy * 12];
        uint32_t bits = 0;
        #pragma unroll
        for (int ox = 0; ox < 12; ++ox) {
            int v = 2 * P[ox] - (int)bp[ox];
            bits |= (v >= T ? 1u : 0u) << ox;
        }
        acc |= (uint64_t)bits << (12 * oy);
    }
    uint32_t w0 = (uint32_t)acc;
    uint32_t w1 = (uint32_t)(acc >> 32) & 0x0FFFFFFFu;

    int bsum = __popc(w0) + __popc(w1);
    #pragma unroll
    for (int off = 32; off > 0; off >>= 1) bsum += __shfl_xor(bsum, off, 64);
    if (lane == 0) Bs[s] = bsum;

    *(uint2*)(h2b + (size_t)s * 128 + 2 * c) = make_uint2(w0, w1);
}

// ---------------------------------------------------------------------------
// lin+out fused: 1024 blocks x 8 samples (R8 was 512 x 16 -> 2 blocks/CU,
// occupancy 17%, s_load latency exposed). LDS ~34 KB -> 4 blocks/CU ->
// 16 waves/CU. Wave = 2 samples; loops all 8 jw tiles through one 32 KB
// LDS buffer; out epilogue in-block.
// ---------------------------------------------------------------------------
__global__ __launch_bounds__(256) void lin_kernel(
    const uint32_t* __restrict__ h2b,
    const uint32_t* __restrict__ wlin4,
    const int* __restrict__ Tlin,
    const int* __restrict__ Bs,
    const uint32_t* __restrict__ wout,
    const float* __restrict__ out_b,
    float* __restrict__ out)
{
    __shared__ uint4    s_w[2048];       // 32 KB weight tile (one jw)
    __shared__ uint64_t s_h3[8][8];      // h3 bits per sample
    __shared__ uint64_t s_wout[10][8];

    int tid  = threadIdx.x;
    int lane = tid & 63;
    int wv   = __builtin_amdgcn_readfirstlane((int)(tid >> 6));
    int sbase = blockIdx.x * 8;

    if (tid < 80) ((uint64_t*)s_wout)[tid] = ((const uint64_t*)wout)[tid];

    int smp = sbase + wv * 2;
    int B0 = Bs[smp], B1 = Bs[smp + 1];

    for (int jw = 0; jw < 8; ++jw) {
        const uint4* wsrc = (const uint4*)wlin4 + (size_t)jw * 2048;
        #pragma unroll
        for (int i = 0; i < 8; ++i)
            s_w[i * 256 + tid] = wsrc[i * 256 + tid];
        int T = Tlin[jw * 64 + lane];
        __syncthreads();

        int P0 = 0, P1 = 0;
        const uint4* a0p = (const uint4*)(h2b + (size_t)smp * 128);
        const uint4* a1p = (const uint4*)(h2b + (size_t)(smp + 1) * 128);
        #pragma unroll 8
        for (int kq = 0; kq < 32; ++kq) {
            uint4 w4 = s_w[kq * 64 + lane];
            uint4 a0 = a0p[kq];                      // uniform -> s_load
            uint4 a1 = a1p[kq];
            P0 += __popc(a0.x & w4.x); P1 += __popc(a1.x & w4.x);
            P0 += __popc(a0.y & w4.y); P1 += __popc(a1.y & w4.y);
            P0 += __popc(a0.z & w4.z); P1 += __popc(a1.z & w4.z);
            P0 += __popc(a0.w & w4.w); P1 += __popc(a1.w & w4.w);
        }
        uint64_t mk0 = __ballot(2 * P0 >= T + B0);
        uint64_t mk1 = __ballot(2 * P1 >= T + B1);
        if (lane == 0) {
            s_h3[wv * 2][jw]     = mk0;
            s_h3[wv * 2 + 1][jw] = mk1;
        }
        __syncthreads();
    }

    // out epilogue: 80 tasks = 8 samples x 10 outputs
    if (tid < 80) {
        int sl = tid / 10, o = tid - sl * 10;
        int P = 0, B = 0;
        #pragma unroll
        for (int k = 0; k < 8; ++k) {
            uint64_t a = s_h3[sl][k];
            P += __popcll(a & s_wout[o][k]);
            B += __popcll(a);
        }
        out[(size_t)(sbase + sl) * 10 + o] = __fadd_rn((float)(2 * P - B), out_b[o]);
    }
}

// ---------------------------------------------------------------------------
extern "C" void kernel_launch(void* const* d_in, const int* in_sizes, int n_in,
                              void* d_out, int out_size, void* d_ws, size_t ws_size,
                              hipStream_t stream)
{
    const float* x       = (const float*)d_in[0];
    const float* conv1_w = (const float*)d_in[1];
    const float* conv1_b = (const float*)d_in[2];
    const float* bn1_g   = (const float*)d_in[3];
    const float* bn1_b   = (const float*)d_in[4];
    const float* bn1_m   = (const float*)d_in[5];
    const float* bn1_v   = (const float*)d_in[6];
    const float* conv2_w = (const float*)d_in[7];
    const float* conv2_b = (const float*)d_in[8];
    const float* bn2_g   = (const float*)d_in[9];
    const float* bn2_b   = (const float*)d_in[10];
    const float* bn2_m   = (const float*)d_in[11];
    const float* bn2_v   = (const float*)d_in[12];
    const float* lin_w   = (const float*)d_in[13];
    const float* lin_b   = (const float*)d_in[14];
    const float* out_w   = (const float*)d_in[15];
    const float* out_b   = (const float*)d_in[16];

    char* ws = (char*)d_ws;
    uint32_t* h2b   = (uint32_t*)(ws + 0);
    uint32_t* wlin4 = (uint32_t*)(ws + 4718592);
    uint32_t* cdat  = (uint32_t*)(ws + 4980736);
    uint32_t* lut   = (uint32_t*)(ws + 4983296);
    uint32_t* wout  = (uint32_t*)(ws + 4985344);
    int*      Tlin  = (int*)     (ws + 4985984);
    int*      Bs    = (int*)     (ws + 4988032);

    pack_kernel<<<258, 256, 0, stream>>>(conv1_w, conv1_b, conv2_w, conv2_b,
                                         lin_w, lin_b, out_w,
                                         bn1_g, bn1_b, bn1_m, bn1_v,
                                         bn2_g, bn2_b, bn2_m, bn2_v,
                                         wlin4, cdat, lut, wout, Tlin);
    conv_kernel<<<NB / 4, 256, 0, stream>>>(x, cdat, lut, h2b, Bs);
    lin_kernel<<<1024, 256, 0, stream>>>(h2b, wlin4, Tlin, Bs, wout, out_b,
                                         (float*)d_out);
}

// Round 10
// 194.797 us; speedup vs baseline: 1.0476x; 1.0476x over previous
//
#include <hip/hip_runtime.h>
#include <cstdint>

#define BN_EPS 1e-5f

static constexpr int NB = 8192;
static constexpr int JLIN = 500;

typedef int v4i  __attribute__((ext_vector_type(4)));
typedef int v16i __attribute__((ext_vector_type(16)));

// ---------------------------------------------------------------------------
// ws layout
//  h2b    [8192][128] u32      @ 0         4 MB  (bit-packed, row-major/sample)
//  wbfrag [16][128][64] uint4  @ 4194304   2 MB  (B fragments in lane order:
//                                                 jt, kq, lane -> 16 i8 = +-1/0)
//  h3w    [8192][16] u32       @ 6291456   512 KB (j-word-major per sample)
//  cdat   [640] u32            @ 6815744
//  lut    [512] u32            @ 6818304
//  wout   [160] u32            @ 6820352
//  Tlin   [512] i32            @ 6820992
//  Bs     [8192] i32           @ 6823040   (conv legacy; unused downstream)
// ---------------------------------------------------------------------------

// ---------------------------------------------------------------------------
// pack kernel, grid = 520 blocks:
//  blocks 0..511  : wbfrag (thread = one 16-byte B fragment slot)
//  blocks 512,513 : conv1 LUT
//  blocks 514..519: cdat masks | Tc2 | Tlin | wout
// ---------------------------------------------------------------------------
__global__ __launch_bounds__(256) void pack_kernel(
    const float* __restrict__ conv1_w, const float* __restrict__ conv1_b,
    const float* __restrict__ conv2_w, const float* __restrict__ conv2_b,
    const float* __restrict__ lin_w, const float* __restrict__ lin_b,
    const float* __restrict__ out_w,
    const float* __restrict__ bn1_g, const float* __restrict__ bn1_b,
    const float* __restrict__ bn1_m, const float* __restrict__ bn1_v,
    const float* __restrict__ bn2_g, const float* __restrict__ bn2_b,
    const float* __restrict__ bn2_m, const float* __restrict__ bn2_v,
    uint4* __restrict__ wbfrag, uint32_t* __restrict__ cdat,
    uint32_t* __restrict__ lut, uint32_t* __restrict__ wout,
    int* __restrict__ Tlin)
{
    __shared__ float    s_c1w[288];
    __shared__ uint32_t s_wp[32];
    __shared__ float    s_inv1[32], s_sh1[32], s_b1[32];

    int tid = threadIdx.x;
    int b   = blockIdx.x;

    if (b < 512) {
        // ---- B fragment: jt (j-tile), kq (k-word), lane; 16 bytes ----
        int e  = b * 256 + tid;             // 0..131071
        int L  = e & 63;
        int kq = (e >> 6) & 127;
        int jt = e >> 13;                   // 0..15
        int j  = jt * 32 + (L & 31);
        int h  = L >> 5;
        uint32_t dd[4] = {0u, 0u, 0u, 0u};
        if (j < JLIN) {
            int c  = kq >> 1, hi = kq & 1;
            int nb = (hi ? 28 : 32) - 16 * h;   // valid bytes in this group
            const float* src = lin_w + (size_t)j * 3840 + c * 60 + hi * 32 + 16 * h;
            #pragma unroll
            for (int i = 0; i < 16; ++i) {
                uint32_t byte = 0;
                if (i < nb) byte = (src[i] > 0.0f) ? 0x01u : 0xFFu;   // +1 / -1 i8
                dd[i >> 2] |= byte << (8 * (i & 3));
            }
        }
        wbfrag[e] = make_uint4(dd[0], dd[1], dd[2], dd[3]);
        return;
    }

    int mb = b - 512;
    if (mb < 2) {
        // ---- conv1 LUT, LDS-staged ----
        for (int i = tid; i < 288; i += 256) s_c1w[i] = conv1_w[i];
        __syncthreads();
        if (tid < 32) {
            uint32_t wp = 0;
            for (int t = 0; t < 9; ++t)
                wp |= (s_c1w[tid * 9 + t] < 0.0f ? 1u : 0u) << t;
            s_wp[tid] = wp;
            float inv = bn1_g[tid] / sqrtf(bn1_v[tid] + BN_EPS);
            s_inv1[tid] = inv;
            s_sh1[tid]  = bn1_b[tid] - bn1_m[tid] * inv;
            s_b1[tid]   = conv1_b[tid];
        }
        __syncthreads();
        uint32_t px = (uint32_t)(mb * 256 + tid);     // 0..511
        uint32_t word = 0;
        for (int c = 0; c < 32; ++c) {
            int d = 9 - 2 * __popc(px ^ s_wp[c]);
            float z = __fadd_rn((float)d, s_b1[c]);
            z = __fadd_rn(__fmul_rn(z, s_inv1[c]), s_sh1[c]);
            word |= (z > 0.0f ? 1u : 0u) << c;
        }
        lut[px] = word;
        return;
    }

    int idx = (mb - 2) * 256 + tid;     // 0..1535
    if (idx < 576) {
        // conv2 masks, plane-major [tap][c] (complemented when inv < 0)
        int c = idx / 9, tap = idx % 9;
        uint32_t w = 0;
        for (int ic = 0; ic < 32; ++ic)
            w |= (conv2_w[c * 288 + ic * 9 + tap] > 0.0f ? 1u : 0u) << ic;
        float inv = bn2_g[c] / sqrtf(bn2_v[c] + BN_EPS);
        if (inv < 0.0f) w = ~w;
        cdat[tap * 64 + c] = w;
    } else if (idx < 576 + 64) {
        // conv2 integer thresholds (exact monotone scan)
        int c = idx - 576;
        float inv = bn2_g[c] / sqrtf(bn2_v[c] + BN_EPS);
        float sh  = bn2_b[c] - bn2_m[c] * inv;
        float b2  = conv2_b[c];
        int T = 10000;
        for (int u = -300; u <= 300; ++u) {
            float v = (inv < 0.0f) ? (float)(-u) : (float)u;
            float z = __fadd_rn(__fmul_rn(__fadd_rn(v, b2), inv), sh);
            if (z > 0.0f) { T = u; break; }
        }
        cdat[576 + c] = (uint32_t)T;
    } else if (idx < 576 + 64 + 512) {
        // lin integer thresholds (on D = 2P-B directly)
        int j = idx - (576 + 64);
        int T = 10000;
        if (j < JLIN) {
            float lb = lin_b[j];
            int base = (int)floorf(-lb) - 2;
            for (int u = base; u <= base + 5; ++u)
                if (__fadd_rn((float)u, lb) > 0.0f) { T = u; break; }
        }
        Tlin[j] = T;
    } else if (idx < 576 + 64 + 512 + 160) {
        int t = idx - (576 + 64 + 512);
        int j = t >> 4, k = t & 15;
        uint32_t w = 0;
        for (int bb = 0; bb < 32; ++bb) {
            int jj = k * 32 + bb;
            if (jj < JLIN) w |= (out_w[j * 500 + jj] > 0.0f ? 1u : 0u) << bb;
        }
        wout[t] = w;
    }
}

// ---------------------------------------------------------------------------
// conv kernel: 4 samples/block (wave = sample), 2048 blocks. Unchanged (R9).
// ---------------------------------------------------------------------------
__global__ __launch_bounds__(256) void conv_kernel(
    const float* __restrict__ x,
    const uint32_t* __restrict__ cdat,
    const uint32_t* __restrict__ lut,
    uint32_t* __restrict__ h2b, int* __restrict__ Bs)
{
    __shared__ __align__(8) uint32_t s_flat[4][44];
    __shared__ uint32_t s_lut[512];
    __shared__ __align__(8) uint32_t s_in[4][288];   // 286 used
    __shared__ uint32_t s_base[4][64];

    int tid  = threadIdx.x;
    int lane = tid & 63;
    int wv   = tid >> 6;
    int s    = blockIdx.x * 4 + wv;

    s_lut[tid]       = lut[tid];
    s_lut[tid + 256] = lut[tid + 256];

    // ph1: flat sign bitmap (1296 bits -> 21 ballots, coalesced)
    const float* xs = x + (size_t)s * 1296;
    #pragma unroll
    for (int it = 0; it < 21; ++it) {
        int f = it * 64 + lane;
        float v = (f < 1296) ? xs[f] : 1.0f;
        uint64_t mk = __ballot(v < 0.0f);
        if (lane == 0) *((uint64_t*)&s_flat[wv][2 * it]) = mk;
    }
    __syncthreads();

    // ph2: conv1 via LUT
    for (int i = tid; i < 4 * 286; i += 256) {
        int sl = i / 286, p = i - sl * 286;
        int oy = p / 26, ox = p - oy * 26;
        uint32_t pxb = 0;
        #pragma unroll
        for (int ky = 0; ky < 3; ++ky) {
            int bitpos = 54 * (2 * oy + ky) + 2 * ox;
            int d  = bitpos >> 5;
            int sh = bitpos & 31;
            uint64_t wp = (uint64_t)s_flat[sl][d] | ((uint64_t)s_flat[sl][d + 1] << 32);
            pxb |= (((uint32_t)(wp >> sh)) & 7u) << (3 * ky);
        }
        s_in[sl][p] = s_lut[pxb];
    }
    __syncthreads();

    // ph2.5: window popcount base per output position
    for (int i = tid; i < 4 * 60; i += 256) {
        int sl = i / 60, p = i - sl * 60;
        int oy = p / 12, ox = p - 12 * oy;
        uint32_t sum = 0;
        #pragma unroll
        for (int ky = 0; ky < 3; ++ky) {
            const uint32_t* rp = &s_in[sl][(2 * oy + ky) * 26 + 2 * ox];
            sum += __popc(rp[0]) + __popc(rp[1]) + __popc(rp[2]);
        }
        s_base[sl][p] = sum;
    }
    __syncthreads();

    // ph3: lane = channel; row-at-a-time to bound register pressure
    int c = lane;
    uint32_t m[9];
    #pragma unroll
    for (int q = 0; q < 9; ++q) m[q] = cdat[q * 64 + c];   // coalesced
    int T = (int)cdat[576 + c];

    uint64_t acc = 0;
    for (int oy = 0; oy < 5; ++oy) {
        int P[12];
        #pragma unroll
        for (int ox = 0; ox < 12; ++ox) P[ox] = 0;
        #pragma unroll
        for (int ky = 0; ky < 3; ++ky) {
            const uint32_t* rp = &s_in[wv][(2 * oy + ky) * 26];
            uint32_t r[25];
            #pragma unroll
            for (int d = 0; d < 12; ++d)
                *(uint64_t*)&r[2 * d] = *(const uint64_t*)&rp[2 * d];  // b64 broadcast
            r[24] = rp[24];
            uint32_t m0 = m[ky * 3 + 0], m1 = m[ky * 3 + 1], m2 = m[ky * 3 + 2];
            #pragma unroll
            for (int ox = 0; ox < 12; ++ox) {
                P[ox] += __popc(r[2 * ox]     & m0);
                P[ox] += __popc(r[2 * ox + 1] & m1);
                P[ox] += __popc(r[2 * ox + 2] & m2);
            }
        }
        const uint32_t* bp = &s_base[wv][oy * 12];
        uint32_t bits = 0;
        #pragma unroll
        for (int ox = 0; ox < 12; ++ox) {
            int v = 2 * P[ox] - (int)bp[ox];
            bits |= (v >= T ? 1u : 0u) << ox;
        }
        acc |= (uint64_t)bits << (12 * oy);
    }
    uint32_t w0 = (uint32_t)acc;
    uint32_t w1 = (uint32_t)(acc >> 32) & 0x0FFFFFFFu;

    int bsum = __popc(w0) + __popc(w1);
    #pragma unroll
    for (int off = 32; off > 0; off >>= 1) bsum += __shfl_xor(bsum, off, 64);
    if (lane == 0) Bs[s] = bsum;

    *(uint2*)(h2b + (size_t)s * 128 + 2 * c) = make_uint2(w0, w1);
}

// ---------------------------------------------------------------------------
// lin2: i8 MFMA GEMM. D[s][j] = sum_k a[s][k] * w[j][k], a in {0,1}, w = +-1.
// Block = 64 samples x 4 j-tiles (one per wave); wave = two 32x32 acc tiles.
// K = 4096 padded bit-slots (h2b's 128 words; zero slots contribute 0).
// Per 16-word chunk: expand bits -> i8 bytes in LDS (stride 520 = 2-way-free
// banks, 8B aligned), then 16 kq x (1 coalesced B-frag load + 4 ds_read_b64
// + 2 mfma). B fragments prebuilt in exact lane order by pack.
// A/B use the SAME k-slot convention, so any k-permutation cancels in sum_k.
// C/D map (HW-verified): col=lane&31, row=(reg&3)+8*(reg>>2)+4*(lane>>5).
// ---------------------------------------------------------------------------
__global__ __launch_bounds__(256) void lin2_kernel(
    const uint32_t* __restrict__ h2b,
    const uint4* __restrict__ wbfrag,
    const int* __restrict__ Tlin,
    uint32_t* __restrict__ h3w)
{
    __shared__ uint8_t As[64 * 520];     // 33,280 B

    int tid  = threadIdx.x;
    int lane = tid & 63;
    int wv   = __builtin_amdgcn_readfirstlane((int)(tid >> 6));
    int sblk = blockIdx.x >> 2;          // 0..127
    int jgrp = blockIdx.x & 3;
    int jt   = jgrp * 4 + wv;            // 0..15
    int s0   = sblk * 64;

    int T = Tlin[jt * 32 + (lane & 31)];
    int row  = lane & 31;
    int half = lane >> 5;

    v16i acc0 = {};
    v16i acc1 = {};

    for (int chunk = 0; chunk < 8; ++chunk) {
        // expand 64 samples x 16 words -> {0,1} bytes
        for (int e = tid; e < 1024; e += 256) {
            int sm = e >> 4, wl = e & 15;
            uint32_t w = h2b[(size_t)(s0 + sm) * 128 + chunk * 16 + wl];
            uint32_t dw[8];
            #pragma unroll
            for (int q = 0; q < 8; ++q)
                dw[q] = (((w >> (4 * q)) & 0xFu) * 0x204081u) & 0x01010101u;
            uint64_t* dst = (uint64_t*)(As + sm * 520 + wl * 32);
            dst[0] = (uint64_t)dw[0] | ((uint64_t)dw[1] << 32);
            dst[1] = (uint64_t)dw[2] | ((uint64_t)dw[3] << 32);
            dst[2] = (uint64_t)dw[4] | ((uint64_t)dw[5] << 32);
            dst[3] = (uint64_t)dw[6] | ((uint64_t)dw[7] << 32);
        }
        __syncthreads();

        const uint4* bsrc = wbfrag + ((size_t)jt * 128 + chunk * 16) * 64 + lane;
        #pragma unroll 4
        for (int kq = 0; kq < 16; ++kq) {
            uint4 bw = bsrc[kq * 64];
            v4i bf = {(int)bw.x, (int)bw.y, (int)bw.z, (int)bw.w};
            const uint8_t* ap = As + row * 520 + kq * 32 + half * 16;
            uint64_t lo0 = *(const uint64_t*)ap;
            uint64_t hi0 = *(const uint64_t*)(ap + 8);
            const uint8_t* aq = ap + 32 * 520;
            uint64_t lo1 = *(const uint64_t*)aq;
            uint64_t hi1 = *(const uint64_t*)(aq + 8);
            v4i a0 = {(int)(uint32_t)lo0, (int)(lo0 >> 32),
                      (int)(uint32_t)hi0, (int)(hi0 >> 32)};
            v4i a1 = {(int)(uint32_t)lo1, (int)(lo1 >> 32),
                      (int)(uint32_t)hi1, (int)(hi1 >> 32)};
            acc0 = __builtin_amdgcn_mfma_i32_32x32x32_i8(a0, bf, acc0, 0, 0, 0);
            acc1 = __builtin_amdgcn_mfma_i32_32x32x32_i8(a1, bf, acc1, 0, 0, 0);
        }
        __syncthreads();
    }

    // epilogue: threshold + ballot -> h3w[s][jt] (j-word jt covers j 32jt..+31)
    #pragma unroll
    for (int r = 0; r < 16; ++r) {
        int row0 = (r & 3) + 8 * (r >> 2);
        uint64_t mk0 = __ballot(acc0[r] >= T);
        uint64_t mk1 = __ballot(acc1[r] >= T);
        if (lane == 0) {
            h3w[(size_t)(s0 + row0) * 16 + jt]          = (uint32_t)mk0;
            h3w[(size_t)(s0 + row0 + 4) * 16 + jt]      = (uint32_t)(mk0 >> 32);
            h3w[(size_t)(s0 + 32 + row0) * 16 + jt]     = (uint32_t)mk1;
            h3w[(size_t)(s0 + 32 + row0 + 4) * 16 + jt] = (uint32_t)(mk1 >> 32);
        }
    }
}

// ---------------------------------------------------------------------------
// out kernel: thread = sample; reads its 16 h3 words once, all 10 outputs.
// ---------------------------------------------------------------------------
__global__ __launch_bounds__(256) void out_kernel(
    const uint32_t* __restrict__ h3w,
    const uint32_t* __restrict__ wout,
    const float* __restrict__ out_b,
    float* __restrict__ out)
{
    int s = blockIdx.x * 256 + threadIdx.x;   // 0..8191
    const uint4* hp = (const uint4*)(h3w + (size_t)s * 16);
    uint4 q0 = hp[0], q1 = hp[1], q2 = hp[2], q3 = hp[3];
    uint32_t w[16] = {q0.x, q0.y, q0.z, q0.w, q1.x, q1.y, q1.z, q1.w,
                      q2.x, q2.y, q2.z, q2.w, q3.x, q3.y, q3.z, q3.w};
    int B = 0;
    #pragma unroll
    for (int k = 0; k < 16; ++k) B += __popc(w[k]);
    #pragma unroll
    for (int o = 0; o < 10; ++o) {
        int P = 0;
        #pragma unroll
        for (int k = 0; k < 16; ++k) P += __popc(w[k] & wout[o * 16 + k]);
        out[(size_t)s * 10 + o] = __fadd_rn((float)(2 * P - B), out_b[o]);
    }
}

// ---------------------------------------------------------------------------
extern "C" void kernel_launch(void* const* d_in, const int* in_sizes, int n_in,
                              void* d_out, int out_size, void* d_ws, size_t ws_size,
                              hipStream_t stream)
{
    const float* x       = (const float*)d_in[0];
    const float* conv1_w = (const float*)d_in[1];
    const float* conv1_b = (const float*)d_in[2];
    const float* bn1_g   = (const float*)d_in[3];
    const float* bn1_b   = (const float*)d_in[4];
    const float* bn1_m   = (const float*)d_in[5];
    const float* bn1_v   = (const float*)d_in[6];
    const float* conv2_w = (const float*)d_in[7];
    const float* conv2_b = (const float*)d_in[8];
    const float* bn2_g   = (const float*)d_in[9];
    const float* bn2_b   = (const float*)d_in[10];
    const float* bn2_m   = (const float*)d_in[11];
    const float* bn2_v   = (const float*)d_in[12];
    const float* lin_w   = (const float*)d_in[13];
    const float* lin_b   = (const float*)d_in[14];
    const float* out_w   = (const float*)d_in[15];
    const float* out_b   = (const float*)d_in[16];

    char* ws = (char*)d_ws;
    uint32_t* h2b    = (uint32_t*)(ws + 0);
    uint4*    wbfrag = (uint4*)   (ws + 4194304);
    uint32_t* h3w    = (uint32_t*)(ws + 6291456);
    uint32_t* cdat   = (uint32_t*)(ws + 6815744);
    uint32_t* lut    = (uint32_t*)(ws + 6818304);
    uint32_t* wout   = (uint32_t*)(ws + 6820352);
    int*      Tlin   = (int*)     (ws + 6820992);
    int*      Bs     = (int*)     (ws + 6823040);

    pack_kernel<<<520, 256, 0, stream>>>(conv1_w, conv1_b, conv2_w, conv2_b,
                                         lin_w, lin_b, out_w,
                                         bn1_g, bn1_b, bn1_m, bn1_v,
                                         bn2_g, bn2_b, bn2_m, bn2_v,
                                         wbfrag, cdat, lut, wout, Tlin);
    conv_kernel<<<NB / 4, 256, 0, stream>>>(x, cdat, lut, h2b, Bs);
    lin2_kernel<<<512, 256, 0, stream>>>(h2b, wbfrag, Tlin, h3w);
    out_kernel<<<32, 256, 0, stream>>>(h3w, wout, out_b, (float*)d_out);
}

// Round 11
// 190.522 us; speedup vs baseline: 1.0712x; 1.0224x over previous
//
#include <hip/hip_runtime.h>
#include <cstdint>

#define BN_EPS 1e-5f

static constexpr int NB = 8192;
static constexpr int JLIN = 500;

typedef int v4i  __attribute__((ext_vector_type(4)));
typedef int v16i __attribute__((ext_vector_type(16)));

// ---------------------------------------------------------------------------
// ws layout
//  h2b    [8192][128] u32      @ 0         4 MB  (bit-packed, row-major/sample)
//  wbfrag [16][128][64] uint4  @ 4194304   2 MB  (lin B frags, lane order)
//  h3w    [8192][16] u32       @ 6291456   512 KB
//  cdat   [640] u32            @ 6815744   (thresholds at [576..639]; masks legacy)
//  lut    [512] u32            @ 6818304
//  wout   [160] u32            @ 6820352
//  Tlin   [512] i32            @ 6820992
//  (gap: Bs legacy)            @ 6823040
//  wcfrag [9][2][64] uint4     @ 6855808   18 KB (conv2 B frags, lane order,
//                                           bytes = sign(w)*chsign, +-1)
// ---------------------------------------------------------------------------

// ---------------------------------------------------------------------------
// pack kernel, grid = 525 blocks:
//  0..511   : wbfrag (lin)     512,513: conv1 LUT    514..519: misc
//  520..524 : wcfrag (conv2 MFMA B fragments)
// ---------------------------------------------------------------------------
__global__ __launch_bounds__(256) void pack_kernel(
    const float* __restrict__ conv1_w, const float* __restrict__ conv1_b,
    const float* __restrict__ conv2_w, const float* __restrict__ conv2_b,
    const float* __restrict__ lin_w, const float* __restrict__ lin_b,
    const float* __restrict__ out_w,
    const float* __restrict__ bn1_g, const float* __restrict__ bn1_b,
    const float* __restrict__ bn1_m, const float* __restrict__ bn1_v,
    const float* __restrict__ bn2_g, const float* __restrict__ bn2_b,
    const float* __restrict__ bn2_m, const float* __restrict__ bn2_v,
    uint4* __restrict__ wbfrag, uint32_t* __restrict__ cdat,
    uint32_t* __restrict__ lut, uint32_t* __restrict__ wout,
    int* __restrict__ Tlin, uint4* __restrict__ wcfrag)
{
    __shared__ float    s_c1w[288];
    __shared__ uint32_t s_wp[32];
    __shared__ float    s_inv1[32], s_sh1[32], s_b1[32];

    int tid = threadIdx.x;
    int b   = blockIdx.x;

    if (b < 512) {
        // ---- lin B fragment: jt, kq, lane; 16 i8 ----
        int e  = b * 256 + tid;
        int L  = e & 63;
        int kq = (e >> 6) & 127;
        int jt = e >> 13;
        int j  = jt * 32 + (L & 31);
        int h  = L >> 5;
        uint32_t dd[4] = {0u, 0u, 0u, 0u};
        if (j < JLIN) {
            int c  = kq >> 1, hi = kq & 1;
            int nb = (hi ? 28 : 32) - 16 * h;
            const float* src = lin_w + (size_t)j * 3840 + c * 60 + hi * 32 + 16 * h;
            #pragma unroll
            for (int i = 0; i < 16; ++i) {
                uint32_t byte = 0;
                if (i < nb) byte = (src[i] > 0.0f) ? 0x01u : 0xFFu;
                dd[i >> 2] |= byte << (8 * (i & 3));
            }
        }
        wbfrag[e] = make_uint4(dd[0], dd[1], dd[2], dd[3]);
        return;
    }

    if (b >= 520) {
        // ---- conv2 B fragment: idx = t*128 + n*64 + L ----
        int e = (b - 520) * 256 + tid;      // 0..1279, use <1152
        if (e < 1152) {
            int t = e >> 7;                 // tap 0..8 (ky*3+kx)
            int n = (e >> 6) & 1;
            int L = e & 63;
            int c = n * 32 + (L & 31);
            int hb = L >> 5;
            bool flip = (bn2_g[c] < 0.0f);  // sign(inv) = sign(gamma)
            uint32_t dd[4] = {0u, 0u, 0u, 0u};
            #pragma unroll
            for (int i = 0; i < 16; ++i) {
                int ic = 16 * hb + i;
                float w = conv2_w[c * 288 + ic * 9 + t];
                uint32_t byte = ((w > 0.0f) == flip) ? 0xFFu : 0x01u;  // -1 / +1
                dd[i >> 2] |= byte << (8 * (i & 3));
            }
            wcfrag[e] = make_uint4(dd[0], dd[1], dd[2], dd[3]);
        }
        return;
    }

    int mb = b - 512;
    if (mb < 2) {
        // ---- conv1 LUT ----
        for (int i = tid; i < 288; i += 256) s_c1w[i] = conv1_w[i];
        __syncthreads();
        if (tid < 32) {
            uint32_t wp = 0;
            for (int t = 0; t < 9; ++t)
                wp |= (s_c1w[tid * 9 + t] < 0.0f ? 1u : 0u) << t;
            s_wp[tid] = wp;
            float inv = bn1_g[tid] / sqrtf(bn1_v[tid] + BN_EPS);
            s_inv1[tid] = inv;
            s_sh1[tid]  = bn1_b[tid] - bn1_m[tid] * inv;
            s_b1[tid]   = conv1_b[tid];
        }
        __syncthreads();
        uint32_t px = (uint32_t)(mb * 256 + tid);
        uint32_t word = 0;
        for (int c = 0; c < 32; ++c) {
            int d = 9 - 2 * __popc(px ^ s_wp[c]);
            float z = __fadd_rn((float)d, s_b1[c]);
            z = __fadd_rn(__fmul_rn(z, s_inv1[c]), s_sh1[c]);
            word |= (z > 0.0f ? 1u : 0u) << c;
        }
        lut[px] = word;
        return;
    }

    int idx = (mb - 2) * 256 + tid;     // 0..1535
    if (idx < 576) {
        // legacy masks (unused by MFMA conv; cheap, kept)
        int c = idx / 9, tap = idx % 9;
        uint32_t w = 0;
        for (int ic = 0; ic < 32; ++ic)
            w |= (conv2_w[c * 288 + ic * 9 + tap] > 0.0f ? 1u : 0u) << ic;
        float inv = bn2_g[c] / sqrtf(bn2_v[c] + BN_EPS);
        if (inv < 0.0f) w = ~w;
        cdat[tap * 64 + c] = w;
    } else if (idx < 576 + 64) {
        // conv2 integer thresholds on D = chsign * conv (exact monotone scan)
        int c = idx - 576;
        float inv = bn2_g[c] / sqrtf(bn2_v[c] + BN_EPS);
        float sh  = bn2_b[c] - bn2_m[c] * inv;
        float b2  = conv2_b[c];
        int T = 10000;
        for (int u = -300; u <= 300; ++u) {
            float v = (inv < 0.0f) ? (float)(-u) : (float)u;
            float z = __fadd_rn(__fmul_rn(__fadd_rn(v, b2), inv), sh);
            if (z > 0.0f) { T = u; break; }
        }
        cdat[576 + c] = (uint32_t)T;
    } else if (idx < 576 + 64 + 512) {
        int j = idx - (576 + 64);
        int T = 10000;
        if (j < JLIN) {
            float lb = lin_b[j];
            int base = (int)floorf(-lb) - 2;
            for (int u = base; u <= base + 5; ++u)
                if (__fadd_rn((float)u, lb) > 0.0f) { T = u; break; }
        }
        Tlin[j] = T;
    } else if (idx < 576 + 64 + 512 + 160) {
        int t = idx - (576 + 64 + 512);
        int j = t >> 4, k = t & 15;
        uint32_t w = 0;
        for (int bb = 0; bb < 32; ++bb) {
            int jj = k * 32 + bb;
            if (jj < JLIN) w |= (out_w[j * 500 + jj] > 0.0f ? 1u : 0u) << bb;
        }
        wout[t] = w;
    }
}

// ---------------------------------------------------------------------------
// conv kernel (MFMA conv2): 2 samples/block, 4096 blocks, wave = (sl, rt).
//  ph1: flat ballot sign-pack (wave -> sample half)
//  ph2: conv1 via LUT, expanded directly to {0,1} bytes in LDS
//  phM: i8 MFMA: rows = 32 positions (tile rt), cols = 64 ch (2 n-tiles),
//       9 accumulating k-steps (taps); A = ds_read_b128 w/ tap-imm offset,
//       B = prebuilt +-1 frags (global, L2-hot). D = chsign*conv directly.
//  epi: threshold -> 32 ballots -> LDS -> per-channel 60-bit word assembly.
// Layout verified on HW by lin2's passing run (same mfma_i32_32x32x32_i8).
// ---------------------------------------------------------------------------
__global__ __launch_bounds__(256) void conv_kernel(
    const float* __restrict__ x,
    const uint32_t* __restrict__ cdat,
    const uint32_t* __restrict__ lut,
    const uint4* __restrict__ wcfrag,
    uint32_t* __restrict__ h2b)
{
    __shared__ __align__(16) uint8_t s_bytes[2 * 286 * 32];   // 18304 B
    __shared__ uint32_t s_lut[512];
    __shared__ __align__(8) uint32_t s_flat[2][44];
    __shared__ uint64_t s_bal[2][2][2][16];                   // [sl][rt][n][r]

    int tid  = threadIdx.x;
    int lane = tid & 63;
    int wv   = tid >> 6;
    int s0   = blockIdx.x * 2;

    s_lut[tid]       = lut[tid];
    s_lut[tid + 256] = lut[tid + 256];

    // ph1: wave (sample = wv>>1, half = wv&1) packs sign bitmap
    {
        int psl = wv >> 1, ph = wv & 1;
        const float* xs = x + (size_t)(s0 + psl) * 1296;
        int it0 = ph * 11, it1 = ph ? 21 : 11;
        for (int it = it0; it < it1; ++it) {
            int f = it * 64 + lane;
            float v = (f < 1296) ? xs[f] : 1.0f;
            uint64_t mk = __ballot(v < 0.0f);
            if (lane == 0) *((uint64_t*)&s_flat[psl][2 * it]) = mk;
        }
    }
    __syncthreads();

    // ph2: conv1 via LUT + expand word -> 32 {0,1} bytes
    for (int i = tid; i < 2 * 286; i += 256) {
        int sl = i / 286, wnd = i - sl * 286;
        int oy = wnd / 26, ox = wnd - oy * 26;
        uint32_t pxb = 0;
        #pragma unroll
        for (int ky = 0; ky < 3; ++ky) {
            int bitpos = 54 * (2 * oy + ky) + 2 * ox;
            int d  = bitpos >> 5;
            int sh = bitpos & 31;
            uint64_t wp = (uint64_t)s_flat[sl][d] | ((uint64_t)s_flat[sl][d + 1] << 32);
            pxb |= (((uint32_t)(wp >> sh)) & 7u) << (3 * ky);
        }
        uint32_t w = s_lut[pxb];
        uint32_t dw[8];
        #pragma unroll
        for (int q = 0; q < 8; ++q)
            dw[q] = (((w >> (4 * q)) & 0xFu) * 0x204081u) & 0x01010101u;
        uint4* dst = (uint4*)(s_bytes + ((size_t)sl * 286 + wnd) * 32);
        dst[0] = make_uint4(dw[0], dw[1], dw[2], dw[3]);
        dst[1] = make_uint4(dw[4], dw[5], dw[6], dw[7]);
    }
    __syncthreads();

    // phM: wave = (sl = wv>>1, rt = wv&1)
    {
        int sl = wv >> 1, rt = wv & 1;
        int p = rt * 32 + (lane & 31);
        if (p > 59) p = 59;                       // pad rows read valid mem
        int oy = p / 12, ox = p - 12 * oy;
        int hb = lane >> 5;
        const uint8_t* abase = s_bytes + ((size_t)sl * 286 + 52 * oy + 2 * ox) * 32 + 16 * hb;
        const uint4* bbase = wcfrag + lane;

        v16i acc0 = {};
        v16i acc1 = {};
        #pragma unroll
        for (int t = 0; t < 9; ++t) {
            const int koff = (t / 3) * 26 + (t % 3);          // ky*26+kx
            uint4 av = *(const uint4*)(abase + koff * 32);
            v4i af = {(int)av.x, (int)av.y, (int)av.z, (int)av.w};
            uint4 b0 = bbase[t * 128];
            uint4 b1 = bbase[t * 128 + 64];
            v4i bf0 = {(int)b0.x, (int)b0.y, (int)b0.z, (int)b0.w};
            v4i bf1 = {(int)b1.x, (int)b1.y, (int)b1.z, (int)b1.w};
            acc0 = __builtin_amdgcn_mfma_i32_32x32x32_i8(af, bf0, acc0, 0, 0, 0);
            acc1 = __builtin_amdgcn_mfma_i32_32x32x32_i8(af, bf1, acc1, 0, 0, 0);
        }

        int T0 = (int)cdat[576 + (lane & 31)];
        int T1 = (int)cdat[576 + 32 + (lane & 31)];
        #pragma unroll
        for (int r = 0; r < 16; ++r) {
            uint64_t m0 = __ballot(acc0[r] >= T0);
            uint64_t m1 = __ballot(acc1[r] >= T1);
            if (lane == 0) {
                s_bal[sl][rt][0][r] = m0;
                s_bal[sl][rt][1][r] = m1;
            }
        }
    }
    __syncthreads();

    // epi: thread (sl, c) assembles the channel's 60-bit word
    if (tid < 128) {
        int esl = tid >> 6, c = tid & 63;
        int n = c >> 5, cc = c & 31;
        uint32_t w0 = 0, w1 = 0;
        #pragma unroll 4
        for (int p = 0; p < 60; ++p) {
            int rt = p >> 5, row = p & 31;
            int hh = (row >> 2) & 1;
            int r  = (row & 3) | ((row >> 3) << 2);
            uint32_t bit = (uint32_t)((s_bal[esl][rt][n][r] >> (cc + 32 * hh)) & 1u);
            if (p < 32) w0 |= bit << p; else w1 |= bit << (p - 32);
        }
        *(uint2*)(h2b + (size_t)(s0 + esl) * 128 + 2 * c) = make_uint2(w0, w1);
    }
}

// ---------------------------------------------------------------------------
// lin2: i8 MFMA GEMM (unchanged from R10, HW-verified).
// ---------------------------------------------------------------------------
__global__ __launch_bounds__(256) void lin2_kernel(
    const uint32_t* __restrict__ h2b,
    const uint4* __restrict__ wbfrag,
    const int* __restrict__ Tlin,
    uint32_t* __restrict__ h3w)
{
    __shared__ uint8_t As[64 * 520];     // 33,280 B

    int tid  = threadIdx.x;
    int lane = tid & 63;
    int wv   = __builtin_amdgcn_readfirstlane((int)(tid >> 6));
    int sblk = blockIdx.x >> 2;
    int jgrp = blockIdx.x & 3;
    int jt   = jgrp * 4 + wv;
    int s0   = sblk * 64;

    int T = Tlin[jt * 32 + (lane & 31)];
    int row  = lane & 31;
    int half = lane >> 5;

    v16i acc0 = {};
    v16i acc1 = {};

    for (int chunk = 0; chunk < 8; ++chunk) {
        for (int e = tid; e < 1024; e += 256) {
            int sm = e >> 4, wl = e & 15;
            uint32_t w = h2b[(size_t)(s0 + sm) * 128 + chunk * 16 + wl];
            uint32_t dw[8];
            #pragma unroll
            for (int q = 0; q < 8; ++q)
                dw[q] = (((w >> (4 * q)) & 0xFu) * 0x204081u) & 0x01010101u;
            uint64_t* dst = (uint64_t*)(As + sm * 520 + wl * 32);
            dst[0] = (uint64_t)dw[0] | ((uint64_t)dw[1] << 32);
            dst[1] = (uint64_t)dw[2] | ((uint64_t)dw[3] << 32);
            dst[2] = (uint64_t)dw[4] | ((uint64_t)dw[5] << 32);
            dst[3] = (uint64_t)dw[6] | ((uint64_t)dw[7] << 32);
        }
        __syncthreads();

        const uint4* bsrc = wbfrag + ((size_t)jt * 128 + chunk * 16) * 64 + lane;
        #pragma unroll 4
        for (int kq = 0; kq < 16; ++kq) {
            uint4 bw = bsrc[kq * 64];
            v4i bf = {(int)bw.x, (int)bw.y, (int)bw.z, (int)bw.w};
            const uint8_t* ap = As + row * 520 + kq * 32 + half * 16;
            uint64_t lo0 = *(const uint64_t*)ap;
            uint64_t hi0 = *(const uint64_t*)(ap + 8);
            const uint8_t* aq = ap + 32 * 520;
            uint64_t lo1 = *(const uint64_t*)aq;
            uint64_t hi1 = *(const uint64_t*)(aq + 8);
            v4i a0 = {(int)(uint32_t)lo0, (int)(lo0 >> 32),
                      (int)(uint32_t)hi0, (int)(hi0 >> 32)};
            v4i a1 = {(int)(uint32_t)lo1, (int)(lo1 >> 32),
                      (int)(uint32_t)hi1, (int)(hi1 >> 32)};
            acc0 = __builtin_amdgcn_mfma_i32_32x32x32_i8(a0, bf, acc0, 0, 0, 0);
            acc1 = __builtin_amdgcn_mfma_i32_32x32x32_i8(a1, bf, acc1, 0, 0, 0);
        }
        __syncthreads();
    }

    #pragma unroll
    for (int r = 0; r < 16; ++r) {
        int row0 = (r & 3) + 8 * (r >> 2);
        uint64_t mk0 = __ballot(acc0[r] >= T);
        uint64_t mk1 = __ballot(acc1[r] >= T);
        if (lane == 0) {
            h3w[(size_t)(s0 + row0) * 16 + jt]          = (uint32_t)mk0;
            h3w[(size_t)(s0 + row0 + 4) * 16 + jt]      = (uint32_t)(mk0 >> 32);
            h3w[(size_t)(s0 + 32 + row0) * 16 + jt]     = (uint32_t)mk1;
            h3w[(size_t)(s0 + 32 + row0 + 4) * 16 + jt] = (uint32_t)(mk1 >> 32);
        }
    }
}

// ---------------------------------------------------------------------------
// out kernel (unchanged from R10)
// ---------------------------------------------------------------------------
__global__ __launch_bounds__(256) void out_kernel(
    const uint32_t* __restrict__ h3w,
    const uint32_t* __restrict__ wout,
    const float* __restrict__ out_b,
    float* __restrict__ out)
{
    int s = blockIdx.x * 256 + threadIdx.x;
    const uint4* hp = (const uint4*)(h3w + (size_t)s * 16);
    uint4 q0 = hp[0], q1 = hp[1], q2 = hp[2], q3 = hp[3];
    uint32_t w[16] = {q0.x, q0.y, q0.z, q0.w, q1.x, q1.y, q1.z, q1.w,
                      q2.x, q2.y, q2.z, q2.w, q3.x, q3.y, q3.z, q3.w};
    int B = 0;
    #pragma unroll
    for (int k = 0; k < 16; ++k) B += __popc(w[k]);
    #pragma unroll
    for (int o = 0; o < 10; ++o) {
        int P = 0;
        #pragma unroll
        for (int k = 0; k < 16; ++k) P += __popc(w[k] & wout[o * 16 + k]);
        out[(size_t)s * 10 + o] = __fadd_rn((float)(2 * P - B), out_b[o]);
    }
}

// ---------------------------------------------------------------------------
extern "C" void kernel_launch(void* const* d_in, const int* in_sizes, int n_in,
                              void* d_out, int out_size, void* d_ws, size_t ws_size,
                              hipStream_t stream)
{
    const float* x       = (const float*)d_in[0];
    const float* conv1_w = (const float*)d_in[1];
    const float* conv1_b = (const float*)d_in[2];
    const float* bn1_g   = (const float*)d_in[3];
    const float* bn1_b   = (const float*)d_in[4];
    const float* bn1_m   = (const float*)d_in[5];
    const float* bn1_v   = (const float*)d_in[6];
    const float* conv2_w = (const float*)d_in[7];
    const float* conv2_b = (const float*)d_in[8];
    const float* bn2_g   = (const float*)d_in[9];
    const float* bn2_b   = (const float*)d_in[10];
    const float* bn2_m   = (const float*)d_in[11];
    const float* bn2_v   = (const float*)d_in[12];
    const float* lin_w   = (const float*)d_in[13];
    const float* lin_b   = (const float*)d_in[14];
    const float* out_w   = (const float*)d_in[15];
    const float* out_b   = (const float*)d_in[16];

    char* ws = (char*)d_ws;
    uint32_t* h2b    = (uint32_t*)(ws + 0);
    uint4*    wbfrag = (uint4*)   (ws + 4194304);
    uint32_t* h3w    = (uint32_t*)(ws + 6291456);
    uint32_t* cdat   = (uint32_t*)(ws + 6815744);
    uint32_t* lut    = (uint32_t*)(ws + 6818304);
    uint32_t* wout   = (uint32_t*)(ws + 6820352);
    int*      Tlin   = (int*)     (ws + 6820992);
    uint4*    wcfrag = (uint4*)   (ws + 6855808);

    pack_kernel<<<525, 256, 0, stream>>>(conv1_w, conv1_b, conv2_w, conv2_b,
                                         lin_w, lin_b, out_w,
                                         bn1_g, bn1_b, bn1_m, bn1_v,
                                         bn2_g, bn2_b, bn2_m, bn2_v,
                                         wbfrag, cdat, lut, wout, Tlin, wcfrag);
    conv_kernel<<<NB / 2, 256, 0, stream>>>(x, cdat, lut, wcfrag, h2b);
    lin2_kernel<<<512, 256, 0, stream>>>(h2b, wbfrag, Tlin, h3w);
    out_kernel<<<32, 256, 0, stream>>>(h3w, wout, out_b, (float*)d_out);
}